// Round 2
// baseline (12199.615 us; speedup 1.0000x reference)
//
#include <hip/hip_runtime.h>
#include <hip/hip_bf16.h>
#include <cmath>

#define DEV __device__ __forceinline__

DEV float sigm(float x){ return 1.0f/(1.0f + __expf(-x)); }
DEV float tanhx(float x){
  x = fminf(fmaxf(x, -15.0f), 15.0f);
  float e = __expf(2.0f*x);
  return (e - 1.0f)/(e + 1.0f);
}

// ---------------------------------------------------------------------------
// fold conv1 (1x1, 3->64) into conv2 (3x3, 64->128):
// weff[oc][c][k] = sum_m w2[oc][m][k] * w1[m][c]   (128*3*9 = 3456)
// beff[oc]      = b2[oc] + sum_m (sum_k w2[oc][m][k]) * b1[m]
// ---------------------------------------------------------------------------
__global__ __launch_bounds__(256) void k_fold(const float* __restrict__ w1,
    const float* __restrict__ b1, const float* __restrict__ w2,
    const float* __restrict__ b2, float* __restrict__ weff, float* __restrict__ beff)
{
  int tid = threadIdx.x;
  for (int i = tid; i < 3456; i += 256){
    int oc = i / 27, rem = i % 27, c = rem / 9, k = rem % 9;
    float s = 0.f;
    for (int m = 0; m < 64; ++m)
      s += w2[(oc*64 + m)*9 + k] * w1[m*3 + c];
    weff[i] = s;
  }
  for (int i = tid; i < 128; i += 256){
    float s = b2[i];
    for (int m = 0; m < 64; ++m){
      float t = 0.f;
      for (int k = 0; k < 9; ++k) t += w2[(i*64 + m)*9 + k];
      s += t * b1[m];
    }
    beff[i] = s;
  }
}

// ---------------------------------------------------------------------------
// fused conv2' (3x3, IC=3, OC=128 on 64x512 -> 62x510) + maxpool 2x2/2
// -> p1 (16,128,31,255). Block: 256 thr = 64 conv-cols x 4 conv-rows, 8 oc.
// conv results staged in LDS, pooled, written.
// ---------------------------------------------------------------------------
__global__ __launch_bounds__(256) void k_conv2pool(const float* __restrict__ x,
    const float* __restrict__ weff, const float* __restrict__ beff,
    float* __restrict__ p1)
{
  __shared__ float wl[8*27];
  __shared__ float sm[8][4][66];
  int tx = threadIdx.x & 63, ty = threadIdx.x >> 6;
  int ocb = blockIdx.z & 15, n = blockIdx.z >> 4;
  int oc0 = ocb*8;
  if (threadIdx.x < 216) wl[threadIdx.x] = weff[oc0*27 + threadIdx.x];
  __syncthreads();
  int ow = blockIdx.x*64 + tx;                     // conv col (0..511)
  int oh = blockIdx.y*4 + ty;                      // conv row (0..63)
  int owc = min(ow, 509), ohc = min(oh, 61);       // clamp for loads
  const float* xp = x + ((size_t)n*3*64 + ohc)*512 + owc;
  float iv[27];
  #pragma unroll
  for (int c = 0; c < 3; ++c)
    #pragma unroll
    for (int kh = 0; kh < 3; ++kh)
      #pragma unroll
      for (int kw = 0; kw < 3; ++kw)
        iv[c*9 + kh*3 + kw] = xp[((size_t)c*64 + kh)*512 + kw];
  #pragma unroll
  for (int j = 0; j < 8; ++j){
    float s = beff[oc0 + j];
    const float* wp = &wl[j*27];
    #pragma unroll
    for (int k = 0; k < 27; ++k) s += iv[k]*wp[k];
    sm[j][ty][tx] = s;
  }
  __syncthreads();
  // pooled tile: 8 oc x 2 rows x 32 cols = 512 outputs
  int pr0 = blockIdx.y*2, pc0 = blockIdx.x*32;
  for (int i = threadIdx.x; i < 512; i += 256){
    int pc = i & 31, rem = i >> 5, q = rem & 1, j = rem >> 1;
    int prow = pr0 + q, pcol = pc0 + pc;
    if (prow < 31 && pcol < 255){
      float m0 = fmaxf(sm[j][2*q  ][2*pc], sm[j][2*q  ][2*pc+1]);
      float m1 = fmaxf(sm[j][2*q+1][2*pc], sm[j][2*q+1][2*pc+1]);
      p1[((size_t)(n*128 + oc0 + j)*31 + prow)*255 + pcol] = fmaxf(m0, m1);
    }
  }
}

// ---------------------------------------------------------------------------
// generic VALID 3x3 conv, NCHW; optional fused BN, fused transpose store,
// and fused output subsample (sub=1: compute only even conv coords -> /2 grid).
// block = 256 threads (64 ow x 4 oh); 8 oc accums/thread; weights in LDS.
// ---------------------------------------------------------------------------
__global__ __launch_bounds__(256) void k_conv3(const float* __restrict__ in,
    const float* __restrict__ w, const float* __restrict__ cb,
    const float* __restrict__ bng, const float* __restrict__ bnb,
    const float* __restrict__ bnm, const float* __restrict__ bnv,
    float* __restrict__ out,
    int IC, int OC, int IH, int IW, int OH, int OW,
    int useBN, int transposeOut, int sub)
{
  __shared__ float wl[64*72];                      // [icl][j*9+k]
  int tx = threadIdx.x & 63, ty = threadIdx.x >> 6;
  int ow = blockIdx.x*64 + tx;                     // output coord
  int oh = blockIdx.y*4 + ty;
  int ocTiles = OC >> 3;
  int ocb = blockIdx.z % ocTiles, n = blockIdx.z / ocTiles;
  int oc0 = ocb*8;
  bool valid = (ow < OW) && (oh < OH);
  int owc = min(ow, OW-1) << sub;                  // conv coord, clamped
  int ohc = min(oh, OH-1) << sub;
  float acc[8] = {0.f,0.f,0.f,0.f,0.f,0.f,0.f,0.f};
  const size_t ihw = (size_t)IH*IW;

  for (int ic0 = 0; ic0 < IC; ic0 += 64){
    __syncthreads();
    const float* wsrc = w + (size_t)oc0*IC*9 + (size_t)ic0*9;
    for (int i = threadIdx.x; i < 4608; i += 256){
      int j = i / 576, rem = i - j*576;            // rem = icl*9 + k
      wl[(rem/9)*72 + j*9 + (rem%9)] = wsrc[(size_t)j*IC*9 + rem];
    }
    __syncthreads();
    const float* ip = in + ((size_t)(n*IC + ic0)*IH + ohc)*IW + owc;
    #pragma unroll 2
    for (int icl = 0; icl < 64; ++icl){
      float iv[9];
      #pragma unroll
      for (int kh = 0; kh < 3; ++kh)
        #pragma unroll
        for (int kw = 0; kw < 3; ++kw)
          iv[kh*3+kw] = ip[(size_t)kh*IW + kw];
      const float* wp = &wl[icl*72];
      #pragma unroll
      for (int j = 0; j < 8; ++j){
        float s = iv[0]*wp[j*9];
        #pragma unroll
        for (int k = 1; k < 9; ++k) s += iv[k]*wp[j*9+k];
        acc[j] += s;
      }
      ip += ihw;
    }
  }

  if (valid){
    #pragma unroll
    for (int j = 0; j < 8; ++j){
      int oc = oc0 + j;
      float v = acc[j] + cb[oc];
      if (useBN){
        float sc = bng[oc] * rsqrtf(bnv[oc] + 1e-5f);
        v = v*sc + (bnb[oc] - bnm[oc]*sc);
      }
      if (!transposeOut)
        out[((size_t)(n*OC + oc)*OH + oh)*OW + ow] = v;
      else                                          // (bs,c,w,h)->(bs,w,h,c)
        out[((size_t)(n*OH + oh)*OW + ow)*OC + oc] = v;
    }
  }
}

// ---------------------------------------------------------------------------
// generic VALID maxpool, NCHW (NC collapsed); one thread per output element.
// ---------------------------------------------------------------------------
__global__ __launch_bounds__(256) void k_pool(const float* __restrict__ in,
    float* __restrict__ out, int NC, int IH, int IW, int OH, int OW,
    int kh, int kw, int sh, int sw)
{
  int idx = blockIdx.x*256 + threadIdx.x;
  int total = NC*OH*OW;
  if (idx >= total) return;
  int ow = idx % OW; int tmp = idx / OW; int oh = tmp % OH; int nc = tmp / OH;
  const float* p = in + ((size_t)nc*IH + oh*sh)*IW + (size_t)ow*sw;
  float m = -3.4e38f;
  for (int r = 0; r < kh; ++r)
    for (int c = 0; c < kw; ++c)
      m = fmaxf(m, p[(size_t)r*IW + c]);
  out[idx] = m;
}

// ---------------------------------------------------------------------------
// transpose whh (1024x256) -> UT[dir](256x1024) for coalesced LSTM loads
// ---------------------------------------------------------------------------
__global__ __launch_bounds__(256) void k_transU(const float* __restrict__ Uf,
    const float* __restrict__ Ub, float* __restrict__ UT)
{
  int idx = blockIdx.x*256 + threadIdx.x;          // 2*262144
  int d = idx >> 18; int rem = idx & 262143;
  int k = rem >> 10, g = rem & 1023;
  const float* U = d ? Ub : Uf;
  UT[idx] = U[g*256 + k];
}

// ---------------------------------------------------------------------------
// input projection: pre[t*160+r][g] = rows[r][t][:] . W[g][:] + (bih+bhh)[g]
// M=19520 (=305*64), N=1024, K=512; 64x64 tile, BK=32.
// ---------------------------------------------------------------------------
__global__ __launch_bounds__(256) void k_gemm_pre(const float* __restrict__ Arows,
    const float* __restrict__ W, const float* __restrict__ b1,
    const float* __restrict__ b2, float* __restrict__ outp)
{
  __shared__ float As[64][36];
  __shared__ float Bs[64][36];
  int tid = threadIdx.x;
  int tx = tid & 15, ty = tid >> 4;
  int g0 = blockIdx.x * 64, m0 = blockIdx.y * 64;
  int srow = tid & 63, skq = tid >> 6;
  int m = m0 + srow; int r = m % 160; int t = m / 160;
  const float* aB = Arows + ((size_t)r*122 + t)*512 + skq*8;
  const float* bB = W + (size_t)(g0 + srow)*512 + skq*8;
  float acc[4][4] = {{0.f}};

  for (int k0 = 0; k0 < 512; k0 += 32){
    float4 a0 = *(const float4*)(aB + k0);
    float4 a1 = *(const float4*)(aB + k0 + 4);
    float4 c0 = *(const float4*)(bB + k0);
    float4 c1 = *(const float4*)(bB + k0 + 4);
    __syncthreads();
    *(float4*)&As[srow][skq*8]   = a0;
    *(float4*)&As[srow][skq*8+4] = a1;
    *(float4*)&Bs[srow][skq*8]   = c0;
    *(float4*)&Bs[srow][skq*8+4] = c1;
    __syncthreads();
    #pragma unroll 8
    for (int kk = 0; kk < 32; ++kk){
      float av[4], bv[4];
      #pragma unroll
      for (int i = 0; i < 4; ++i) av[i] = As[ty*4+i][kk];
      #pragma unroll
      for (int j = 0; j < 4; ++j) bv[j] = Bs[tx*4+j][kk];
      #pragma unroll
      for (int i = 0; i < 4; ++i)
        #pragma unroll
        for (int j = 0; j < 4; ++j)
          acc[i][j] += av[i]*bv[j];
    }
  }

  float4 vb1 = *(const float4*)(b1 + g0 + tx*4);
  float4 vb2 = *(const float4*)(b2 + g0 + tx*4);
  float bx = vb1.x+vb2.x, by = vb1.y+vb2.y, bz = vb1.z+vb2.z, bw = vb1.w+vb2.w;
  #pragma unroll
  for (int i = 0; i < 4; ++i){
    size_t mm = (size_t)(m0 + ty*4 + i);
    float4 v = make_float4(acc[i][0]+bx, acc[i][1]+by, acc[i][2]+bz, acc[i][3]+bw);
    *(float4*)(outp + mm*1024 + g0 + tx*4) = v;
  }
}

// ---------------------------------------------------------------------------
// bidirectional LSTM recurrence. 160 blocks = 80 row-pairs x 2 dirs.
// thread j owns gate-dim j for both rows of its pair; h in LDS; UT from L2.
// backward dir walks t=121..0; writing at original t IS the output flip.
// ---------------------------------------------------------------------------
__global__ __launch_bounds__(256) void k_lstm(const float* __restrict__ pre,
    const float* __restrict__ UT, float* __restrict__ out)
{
  int b = blockIdx.x;
  int dir = (b >= 80) ? 1 : 0;
  int r0 = (b - dir*80)*2;
  int j = threadIdx.x;
  const float* Ut   = UT  + (size_t)dir*262144;
  const float* preD = pre + (size_t)dir*19988480ull;
  __shared__ float h[2][256];
  h[0][j] = 0.f; h[1][j] = 0.f;
  __syncthreads();
  float c0 = 0.f, c1 = 0.f;

  for (int s = 0; s < 122; ++s){
    int t = dir ? (121 - s) : s;
    const float* p0 = preD + ((size_t)t*160 + r0)*1024 + j;
    float a00 = p0[0],    a01 = p0[256],  a02 = p0[512],  a03 = p0[768];
    float a10 = p0[1024], a11 = p0[1280], a12 = p0[1536], a13 = p0[1792];
    const float* up = Ut + j;
    #pragma unroll 4
    for (int k = 0; k < 256; ++k){
      float h0 = h[0][k], h1 = h[1][k];
      float u0 = up[0], u1 = up[256], u2 = up[512], u3 = up[768];
      a00 += h0*u0; a01 += h0*u1; a02 += h0*u2; a03 += h0*u3;
      a10 += h1*u0; a11 += h1*u1; a12 += h1*u2; a13 += h1*u3;
      up += 1024;
    }
    float i0 = sigm(a00), f0 = sigm(a01), g0 = tanhx(a02), o0 = sigm(a03);
    c0 = f0*c0 + i0*g0;
    float nh0 = o0*tanhx(c0);
    float i1 = sigm(a10), f1 = sigm(a11), g1 = tanhx(a12), o1 = sigm(a13);
    c1 = f1*c1 + i1*g1;
    float nh1 = o1*tanhx(c1);
    __syncthreads();
    h[0][j] = nh0; h[1][j] = nh1;
    __syncthreads();
    out[((size_t)r0*122 + t)*512 + dir*256 + j]     = nh0;
    out[((size_t)(r0+1)*122 + t)*512 + dir*256 + j] = nh1;
  }
}

// ---------------------------------------------------------------------------
// host — workspace layout (floats), peak 57,810,944 floats = 220.5 MiB:
//   p1  @ 0          (16,189,440)   y3 @ 27,758,592 (30,052,352)
//   y4  @ 0          (27,758,592)   p2 @ 27,758,592 (26,624,000)
//   p3  @ 0          (12,189,696)   pre@ 0          (39,976,960)
//   UT  @ 40,000,000 (524,288)      weff@40,600,000 beff@40,610,000
//   rows lives in d_out (exactly out_size), overwritten by lstm at the end.
// ---------------------------------------------------------------------------
extern "C" void kernel_launch(void* const* d_in, const int* in_sizes, int n_in,
                              void* d_out, int out_size, void* d_ws, size_t ws_size,
                              hipStream_t stream)
{
  const float* c1w  = (const float*)d_in[1];
  const float* c1b  = (const float*)d_in[2];
  const float* c2w  = (const float*)d_in[3];
  const float* c2b  = (const float*)d_in[4];
  const float* c3w  = (const float*)d_in[5];
  const float* c3b  = (const float*)d_in[6];
  const float* bn1g = (const float*)d_in[7];
  const float* bn1b = (const float*)d_in[8];
  const float* bn1m = (const float*)d_in[9];
  const float* bn1v = (const float*)d_in[10];
  const float* c4w  = (const float*)d_in[11];
  const float* c4b  = (const float*)d_in[12];
  const float* c5w  = (const float*)d_in[13];
  const float* c5b  = (const float*)d_in[14];
  const float* bn2g = (const float*)d_in[15];
  const float* bn2b = (const float*)d_in[16];
  const float* bn2m = (const float*)d_in[17];
  const float* bn2v = (const float*)d_in[18];
  const float* c6w  = (const float*)d_in[19];
  const float* c6b  = (const float*)d_in[20];
  const float* bn3g = (const float*)d_in[21];
  const float* bn3b = (const float*)d_in[22];
  const float* bn3m = (const float*)d_in[23];
  const float* bn3v = (const float*)d_in[24];
  const float* wihf = (const float*)d_in[25];
  const float* whhf = (const float*)d_in[26];
  const float* bihf = (const float*)d_in[27];
  const float* bhhf = (const float*)d_in[28];
  const float* wihb = (const float*)d_in[29];
  const float* whhb = (const float*)d_in[30];
  const float* bihb = (const float*)d_in[31];
  const float* bhhb = (const float*)d_in[32];
  const float* x    = (const float*)d_in[0];

  float* ws   = (float*)d_ws;
  float* p1   = ws;                       // 16,189,440
  float* y3   = ws + 27758592ull;         // 30,052,352
  float* y4   = ws;                       // 27,758,592
  float* p2   = ws + 27758592ull;         // 26,624,000
  float* p3   = ws;                       // 12,189,696
  float* pre  = ws;                       // 39,976,960
  float* UT   = ws + 40000000ull;         // 524,288
  float* weff = ws + 40600000ull;         // 3,456
  float* beff = ws + 40610000ull;         // 128
  float* rows = (float*)d_out;            // 9,994,240 == out_size
  float* out  = (float*)d_out;

  // fold conv1 into conv2
  k_fold<<<1, 256, 0, stream>>>(c1w, c1b, c2w, c2b, weff, beff);
  // fused conv2' + pool1: x -> p1 (16,128,31,255)
  k_conv2pool<<<dim3(8,16,256), 256, 0, stream>>>(x, weff, beff, p1);
  // conv3 + bn1: p1 -> y3 (16,256,29,253)
  k_conv3<<<dim3(4,8,512), 256, 0, stream>>>(p1, c3w, c3b,
      bn1g,bn1b,bn1m,bn1v, y3, 128,256,31,255,29,253, 1,0,0);
  // conv4: y3 -> y4 (16,256,27,251)
  k_conv3<<<dim3(4,7,512), 256, 0, stream>>>(y3, c4w, c4b,
      nullptr,nullptr,nullptr,nullptr, y4, 256,256,29,253,27,251, 0,0,0);
  // maxpool 2x2/1: y4 -> p2 (16,256,26,250)
  { int tot = 4096*26*250;
    k_pool<<<(tot+255)/256, 256, 0, stream>>>(y4, p2, 4096, 27,251,26,250, 2,2,1,1); }
  // conv5 + bn2 + stride-2 subsample: p2 -> p3 (16,512,12,124)
  k_conv3<<<dim3(2,3,1024), 256, 0, stream>>>(p2, c5w, c5b,
      bn2g,bn2b,bn2m,bn2v, p3, 256,512,26,250,12,124, 1,0,1);
  // conv6 + bn3 + transpose: p3 -> rows (160,122,512) in d_out
  k_conv3<<<dim3(2,3,1024), 256, 0, stream>>>(p3, c6w, c6b,
      bn3g,bn3b,bn3m,bn3v, rows, 512,512,12,124,10,122, 1,1,0);
  // transpose whh for coalesced recurrent loads
  k_transU<<<2048, 256, 0, stream>>>(whhf, whhb, UT);
  // input projection GEMMs: rows -> pre, both directions
  k_gemm_pre<<<dim3(16,305), 256, 0, stream>>>(rows, wihf, bihf, bhhf, pre);
  k_gemm_pre<<<dim3(16,305), 256, 0, stream>>>(rows, wihb, bihb, bhhb, pre + 19988480ull);
  // recurrence -> d_out (overwrites rows)
  k_lstm<<<160, 256, 0, stream>>>(pre, UT, out);
}

// Round 3
// 3244.050 us; speedup vs baseline: 3.7606x; 3.7606x over previous
//
#include <hip/hip_runtime.h>
#include <cmath>

#define DEV __device__ __forceinline__

typedef __attribute__((ext_vector_type(8))) short  short8;
typedef __attribute__((ext_vector_type(8))) unsigned short ushort8;
typedef __attribute__((ext_vector_type(4))) float  f32x4;

DEV float sigm(float x){ return 1.0f/(1.0f + __expf(-x)); }
DEV float tanhx(float x){
  x = fminf(fmaxf(x, -15.0f), 15.0f);
  float e = __expf(2.0f*x);
  return (e - 1.0f)/(e + 1.0f);
}
DEV unsigned short f2bf(float f){
  unsigned u = __float_as_uint(f);
  return (unsigned short)((u + 0x7fffu + ((u>>16)&1u)) >> 16);
}
DEV float bf2f(unsigned short h){ return __uint_as_float(((unsigned)h)<<16); }
DEV void split2(float v, unsigned short& hi, unsigned short& lo){
  hi = f2bf(v); lo = f2bf(v - bf2f(hi));
}

#define GLDS(SRC, DST) __builtin_amdgcn_global_load_lds( \
  (const __attribute__((address_space(1))) unsigned int*)(SRC), \
  (__attribute__((address_space(3))) unsigned int*)(DST), 16, 0, 0)

// ---------------------------------------------------------------------------
// fold conv1 (1x1,3->64) into conv2 (3x3,64->128)
// ---------------------------------------------------------------------------
__global__ __launch_bounds__(256) void k_fold(const float* __restrict__ w1,
    const float* __restrict__ b1, const float* __restrict__ w2,
    const float* __restrict__ b2, float* __restrict__ weff, float* __restrict__ beff)
{
  int tid = threadIdx.x;
  for (int i = tid; i < 3456; i += 256){
    int oc = i / 27, rem = i % 27, c = rem / 9, k = rem % 9;
    float s = 0.f;
    for (int m = 0; m < 64; ++m)
      s += w2[(oc*64 + m)*9 + k] * w1[m*3 + c];
    weff[i] = s;
  }
  for (int i = tid; i < 128; i += 256){
    float s = b2[i];
    for (int m = 0; m < 64; ++m){
      float t = 0.f;
      for (int k = 0; k < 9; ++k) t += w2[(i*64 + m)*9 + k];
      s += t * b1[m];
    }
    beff[i] = s;
  }
}

// ---------------------------------------------------------------------------
// conv weight prep: W9T[k][oc][ic] = bf16split(w[oc][ic][k] * bnscale[oc]),
// bias_eff[oc] = cb*sc + shift.
// ---------------------------------------------------------------------------
__global__ __launch_bounds__(256) void k_prepW(const float* __restrict__ w,
    const float* __restrict__ cb, const float* __restrict__ bng,
    const float* __restrict__ bnb, const float* __restrict__ bnm,
    const float* __restrict__ bnv, int useBN, int OC, int IC,
    unsigned short* __restrict__ WH, unsigned short* __restrict__ WL,
    float* __restrict__ bout)
{
  int idx = blockIdx.x*256 + threadIdx.x;
  int tot = OC*IC*9;
  if (idx < tot){
    int k = idx % 9; int t2 = idx/9; int ic = t2 % IC; int oc = t2/IC;
    float sc = useBN ? bng[oc]*rsqrtf(bnv[oc]+1e-5f) : 1.0f;
    unsigned short h,l; split2(w[idx]*sc, h, l);
    size_t o = ((size_t)k*OC + oc)*IC + ic;
    WH[o]=h; WL[o]=l;
  }
  if (idx < OC){
    float sc = useBN ? bng[idx]*rsqrtf(bnv[idx]+1e-5f) : 1.0f;
    float sh = useBN ? (bnb[idx]-bnm[idx]*sc) : 0.f;
    bout[idx] = cb[idx]*sc + sh;
  }
}

// gemm weight prep: WH/WL[oc][ic] = split(w), b = bih+bhh
__global__ __launch_bounds__(256) void k_prepWg(const float* __restrict__ w,
    const float* __restrict__ b1, const float* __restrict__ b2,
    unsigned short* __restrict__ WH, unsigned short* __restrict__ WL,
    float* __restrict__ bout)
{
  int idx = blockIdx.x*256 + threadIdx.x;
  if (idx < 1024*512){
    unsigned short h,l; split2(w[idx], h, l);
    WH[idx]=h; WL[idx]=l;
  }
  if (idx < 1024) bout[idx] = b1[idx] + b2[idx];
}

// ---------------------------------------------------------------------------
// fused conv2' (3x3,IC=3,OC=128) + maxpool2x2/2 -> p1 NHWC bf16 hi/lo (per half)
// ---------------------------------------------------------------------------
__global__ __launch_bounds__(256) void k_conv2pool(const float* __restrict__ x,
    const float* __restrict__ weff, const float* __restrict__ beff,
    unsigned short* __restrict__ p1H, unsigned short* __restrict__ p1L)
{
  __shared__ float wl[8*27];
  __shared__ float sm[8][4][66];
  int tx = threadIdx.x & 63, ty = threadIdx.x >> 6;
  int ocb = blockIdx.z & 15, n = blockIdx.z >> 4;   // n local 0..7
  int oc0 = ocb*8;
  if (threadIdx.x < 216) wl[threadIdx.x] = weff[oc0*27 + threadIdx.x];
  __syncthreads();
  int ow = blockIdx.x*64 + tx;
  int oh = blockIdx.y*4 + ty;
  int owc = min(ow, 509), ohc = min(oh, 61);
  const float* xp = x + ((size_t)n*3*64 + ohc)*512 + owc;
  float iv[27];
  #pragma unroll
  for (int c = 0; c < 3; ++c)
    #pragma unroll
    for (int kh = 0; kh < 3; ++kh)
      #pragma unroll
      for (int kw = 0; kw < 3; ++kw)
        iv[c*9 + kh*3 + kw] = xp[((size_t)c*64 + kh)*512 + kw];
  #pragma unroll
  for (int j = 0; j < 8; ++j){
    float s = beff[oc0 + j];
    const float* wp = &wl[j*27];
    #pragma unroll
    for (int k = 0; k < 27; ++k) s += iv[k]*wp[k];
    sm[j][ty][tx] = s;
  }
  __syncthreads();
  int pr0 = blockIdx.y*2, pc0 = blockIdx.x*32;
  for (int i = threadIdx.x; i < 512; i += 256){
    int pc = i & 31, rem = i >> 5, q = rem & 1, j = rem >> 1;
    int prow = pr0 + q, pcol = pc0 + pc;
    if (prow < 31 && pcol < 255){
      float m0 = fmaxf(sm[j][2*q  ][2*pc], sm[j][2*q  ][2*pc+1]);
      float m1 = fmaxf(sm[j][2*q+1][2*pc], sm[j][2*q+1][2*pc+1]);
      unsigned short h,l; split2(fmaxf(m0,m1), h, l);
      size_t o = (((size_t)(n*31 + prow)*255 + pcol)<<7) + oc0 + j;
      p1H[o] = h; p1L[o] = l;
    }
  }
}

// ---------------------------------------------------------------------------
// split-bf16 implicit-GEMM conv / GEMM.  C[pix][oc] = sum_{k9,ic} A*W.
// BM=128 pix (1 oh row), BN=128 oc, BK=32. 256 thr / 4 waves, mfma 16x16x32.
// A = NHWC bf16 (hi,lo), W = [k][oc][ic] bf16 (hi,lo).  3 products/chunk.
// global_load_lds staging, linear LDS + inverse-swizzled source + swz read.
// ---------------------------------------------------------------------------
__global__ __launch_bounds__(256) void k_igemm(
    const unsigned short* __restrict__ inH, const unsigned short* __restrict__ inL,
    const unsigned short* __restrict__ wH,  const unsigned short* __restrict__ wL,
    const float* __restrict__ bias,
    unsigned short* __restrict__ outH, unsigned short* __restrict__ outL,
    float* __restrict__ outF,
    int IH, int IW, int IC, int OC, int OH, int OW,
    int K9, int sub, int nICc)
{
  __shared__ unsigned short lds[2][16384];  // [AH 4096][AL 4096][BH 4096][BL 4096]
  const int tid  = threadIdx.x;
  const int wv   = tid >> 6, lane = tid & 63;
  const int wr   = wv >> 1,  wc   = wv & 1;
  const int kg   = lane >> 4;
  const int ocTiles = OC >> 7;
  const int ow0 = blockIdx.x << 7;
  const int oh  = blockIdx.y;
  const int ocb = blockIdx.z % ocTiles;
  const int n   = blockIdx.z / ocTiles;
  const int oc0 = ocb << 7;

  // staging source bases (per-lane, inverse-swizzled slot)
  const int sp = tid >> 2, ss = tid & 3;
  size_t aBase[2], bBase[2];
  #pragma unroll
  for (int q = 0; q < 2; ++q){
    int p = q*64 + sp;
    int opix = min(ow0 + p, OW-1);
    int sw = ss ^ ((p>>1)&3);
    aBase[q] = ((size_t)(n*IH + (oh<<sub))*IW + ((size_t)opix<<sub))*IC + sw*8;
    int o = q*64 + sp;
    int swb = ss ^ ((o>>1)&3);
    bBase[q] = (size_t)(oc0 + o)*IC + swb*8;
  }
  // fragment read offsets (swizzled), ushort units
  int aoff[4], boff[4];
  #pragma unroll
  for (int mi = 0; mi < 4; ++mi){
    int pr = wr*64 + mi*16 + (lane&15);
    aoff[mi] = pr*32 + ((kg ^ ((pr>>1)&3))*8);
  }
  #pragma unroll
  for (int nj = 0; nj < 4; ++nj){
    int orow = wc*64 + nj*16 + (lane&15);
    boff[nj] = orow*32 + ((kg ^ ((orow>>1)&3))*8);
  }

  auto STAGE = [&](int buf, int kk, int ic0){
    size_t aOff = ((size_t)((kk/3)*IW + (kk%3)))*IC + ic0;
    size_t bOff = ((size_t)kk*OC)*IC + ic0;
    unsigned short* d0 = &lds[buf][wv*512];
    #pragma unroll
    for (int q = 0; q < 2; ++q){
      GLDS(inH + aBase[q] + aOff, d0 + q*2048);
      GLDS(inL + aBase[q] + aOff, d0 + 4096  + q*2048);
      GLDS(wH  + bBase[q] + bOff, d0 + 8192  + q*2048);
      GLDS(wL  + bBase[q] + bOff, d0 + 12288 + q*2048);
    }
  };

  f32x4 acc[4][4] = {};
  const int NT = K9 * nICc;
  STAGE(0, 0, 0);
  int cur = 0;
  for (int t = 0; t < NT; ++t){
    __syncthreads();
    short8 aH[4], aL[4], bH[4], bL[4];
    #pragma unroll
    for (int mi = 0; mi < 4; ++mi){
      aH[mi] = *(const short8*)&lds[cur][aoff[mi]];
      aL[mi] = *(const short8*)&lds[cur][4096 + aoff[mi]];
    }
    #pragma unroll
    for (int nj = 0; nj < 4; ++nj){
      bH[nj] = *(const short8*)&lds[cur][8192  + boff[nj]];
      bL[nj] = *(const short8*)&lds[cur][12288 + boff[nj]];
    }
    if (t+1 < NT){
      int tn = t+1, kk = tn / nICc, icc = tn - kk*nICc;
      STAGE(cur^1, kk, icc*32);
    }
    #pragma unroll
    for (int mi = 0; mi < 4; ++mi)
      #pragma unroll
      for (int nj = 0; nj < 4; ++nj){
        acc[mi][nj] = __builtin_amdgcn_mfma_f32_16x16x32_bf16(aH[mi], bH[nj], acc[mi][nj],0,0,0);
        acc[mi][nj] = __builtin_amdgcn_mfma_f32_16x16x32_bf16(aL[mi], bH[nj], acc[mi][nj],0,0,0);
        acc[mi][nj] = __builtin_amdgcn_mfma_f32_16x16x32_bf16(aH[mi], bL[nj], acc[mi][nj],0,0,0);
      }
    cur ^= 1;
  }

  // epilogue: C[m][oc] with row=(lane>>4)*4+j, col=lane&15 (m89-verified)
  const int ocL = oc0 + wc*64 + (lane&15);
  const int rb  = wr*64 + ((lane>>4)<<2);
  #pragma unroll
  for (int nj = 0; nj < 4; ++nj){
    int oc = ocL + nj*16;
    float bs = bias[oc];
    #pragma unroll
    for (int mi = 0; mi < 4; ++mi)
      #pragma unroll
      for (int j = 0; j < 4; ++j){
        int pix = ow0 + rb + mi*16 + j;
        if (pix < OW){
          size_t oi = ((size_t)(n*OH + oh)*OW + pix)*OC + oc;
          float v = acc[mi][nj][j] + bs;
          if (outF) outF[oi] = v;
          else { unsigned short h,l; split2(v,h,l); outH[oi]=h; outL[oi]=l; }
        }
      }
  }
}

// ---------------------------------------------------------------------------
// maxpool 2x2/1 on NHWC bf16 hi/lo, per half: (8,27,251,256)->(8,26,250,256)
// ---------------------------------------------------------------------------
__global__ __launch_bounds__(256) void k_pool2(const unsigned short* __restrict__ yH,
    const unsigned short* __restrict__ yL,
    unsigned short* __restrict__ pH, unsigned short* __restrict__ pL)
{
  int idx = blockIdx.x*256 + threadIdx.x;       // over 8*26*250*32
  if (idx >= 1664000) return;
  int g = idx & 31; int t2 = idx >> 5;
  int pw = t2 % 250; t2 /= 250; int ph = t2 % 26; int n = t2 / 26;
  size_t base = (((size_t)(n*27 + ph)*251 + pw)<<8) + g*8;
  float v[8];
  #pragma unroll
  for (int e = 0; e < 8; ++e) v[e] = -3.4e38f;
  #pragma unroll
  for (int r = 0; r < 2; ++r)
    #pragma unroll
    for (int c = 0; c < 2; ++c){
      size_t o = base + ((size_t)(r*251 + c)<<8);
      ushort8 hv = *(const ushort8*)&yH[o];
      ushort8 lv = *(const ushort8*)&yL[o];
      #pragma unroll
      for (int e = 0; e < 8; ++e)
        v[e] = fmaxf(v[e], bf2f(hv[e]) + bf2f(lv[e]));
    }
  ushort8 oh8, ol8;
  #pragma unroll
  for (int e = 0; e < 8; ++e){ unsigned short h,l; split2(v[e],h,l); oh8[e]=h; ol8[e]=l; }
  size_t ob = (((size_t)(n*26 + ph)*250 + pw)<<8) + g*8;
  *(ushort8*)&pH[ob] = oh8;
  *(ushort8*)&pL[ob] = ol8;
}

// ---------------------------------------------------------------------------
// transpose whh (1024x256) -> UT[dir](256x1024)
// ---------------------------------------------------------------------------
__global__ __launch_bounds__(256) void k_transU(const float* __restrict__ Uf,
    const float* __restrict__ Ub, float* __restrict__ UT)
{
  int idx = blockIdx.x*256 + threadIdx.x;
  int d = idx >> 18; int rem = idx & 262143;
  int k = rem >> 10, g = rem & 1023;
  const float* U = d ? Ub : Uf;
  UT[idx] = U[g*256 + k];
}

// ---------------------------------------------------------------------------
// bidirectional LSTM recurrence; pre layout [dir][m=r*122+t][1024] fp32.
// ---------------------------------------------------------------------------
__global__ __launch_bounds__(256) void k_lstm(const float* __restrict__ pre,
    const float* __restrict__ UT, float* __restrict__ out)
{
  int b = blockIdx.x;
  int dir = (b >= 80) ? 1 : 0;
  int r0 = (b - dir*80)*2;
  int j = threadIdx.x;
  const float* Ut   = UT  + (size_t)dir*262144;
  const float* preD = pre + (size_t)dir*19988480ull;
  __shared__ float h[2][256];
  h[0][j] = 0.f; h[1][j] = 0.f;
  __syncthreads();
  float c0 = 0.f, c1 = 0.f;

  for (int s = 0; s < 122; ++s){
    int t = dir ? (121 - s) : s;
    const float* p0 = preD + ((size_t)r0*122 + t)*1024 + j;
    float a00 = p0[0],      a01 = p0[256],      a02 = p0[512],      a03 = p0[768];
    float a10 = p0[124928], a11 = p0[125184],   a12 = p0[125440],   a13 = p0[125696];
    const float* up = Ut + j;
    #pragma unroll 4
    for (int k = 0; k < 256; ++k){
      float h0 = h[0][k], h1 = h[1][k];
      float u0 = up[0], u1 = up[256], u2 = up[512], u3 = up[768];
      a00 += h0*u0; a01 += h0*u1; a02 += h0*u2; a03 += h0*u3;
      a10 += h1*u0; a11 += h1*u1; a12 += h1*u2; a13 += h1*u3;
      up += 1024;
    }
    float i0 = sigm(a00), f0 = sigm(a01), g0 = tanhx(a02), o0 = sigm(a03);
    c0 = f0*c0 + i0*g0;
    float nh0 = o0*tanhx(c0);
    float i1 = sigm(a10), f1 = sigm(a11), g1 = tanhx(a12), o1 = sigm(a13);
    c1 = f1*c1 + i1*g1;
    float nh1 = o1*tanhx(c1);
    __syncthreads();
    h[0][j] = nh0; h[1][j] = nh1;
    __syncthreads();
    out[((size_t)r0*122 + t)*512 + dir*256 + j]     = nh0;
    out[((size_t)(r0+1)*122 + t)*512 + dir*256 + j] = nh1;
  }
}

// ---------------------------------------------------------------------------
// host.  ws layout (float units), peak ~51.44M floats = 206 MB (< proven 231MB):
//  pre @0 (39.98M) | conv arena (per batch-half, reused): y3@0, y4@15.1M,
//  p1@29.0M, p2@0, p3@15.1M | rowsLo @40.0M | weights/UT/biases @45.1M+
// ---------------------------------------------------------------------------
extern "C" void kernel_launch(void* const* d_in, const int* in_sizes, int n_in,
                              void* d_out, int out_size, void* d_ws, size_t ws_size,
                              hipStream_t stream)
{
  const float* x    = (const float*)d_in[0];
  const float* c1w  = (const float*)d_in[1];
  const float* c1b  = (const float*)d_in[2];
  const float* c2w  = (const float*)d_in[3];
  const float* c2b  = (const float*)d_in[4];
  const float* c3w  = (const float*)d_in[5];
  const float* c3b  = (const float*)d_in[6];
  const float* bn1g = (const float*)d_in[7];
  const float* bn1b = (const float*)d_in[8];
  const float* bn1m = (const float*)d_in[9];
  const float* bn1v = (const float*)d_in[10];
  const float* c4w  = (const float*)d_in[11];
  const float* c4b  = (const float*)d_in[12];
  const float* c5w  = (const float*)d_in[13];
  const float* c5b  = (const float*)d_in[14];
  const float* bn2g = (const float*)d_in[15];
  const float* bn2b = (const float*)d_in[16];
  const float* bn2m = (const float*)d_in[17];
  const float* bn2v = (const float*)d_in[18];
  const float* c6w  = (const float*)d_in[19];
  const float* c6b  = (const float*)d_in[20];
  const float* bn3g = (const float*)d_in[21];
  const float* bn3b = (const float*)d_in[22];
  const float* bn3m = (const float*)d_in[23];
  const float* bn3v = (const float*)d_in[24];
  const float* wihf = (const float*)d_in[25];
  const float* whhf = (const float*)d_in[26];
  const float* bihf = (const float*)d_in[27];
  const float* bhhf = (const float*)d_in[28];
  const float* wihb = (const float*)d_in[29];
  const float* whhb = (const float*)d_in[30];
  const float* bihb = (const float*)d_in[31];
  const float* bhhb = (const float*)d_in[32];

  float* ws = (float*)d_ws;
  typedef unsigned short u16;

  float* pre  = ws;                                   // 39,976,960 f
  u16*   y3H  = (u16*)(ws);            u16* y3L = y3H + 15026176ull;
  u16*   y4H  = (u16*)(ws + 15100000ull); u16* y4L = y4H + 13879296ull;
  u16*   p1H  = (u16*)(ws + 29000000ull); u16* p1L = p1H + 8094720ull;
  u16*   p2H  = (u16*)(ws);            u16* p2L = p2H + 13312000ull;
  u16*   p3H  = (u16*)(ws + 15100000ull); u16* p3L = p3H + 6094848ull;
  u16*   rowsL= (u16*)(ws + 40000000ull);             // 9,994,240 u
  float* UT   = ws + 45100000ull;
  u16*   W3H  = (u16*)(ws + 45650000ull); u16* W3L = (u16*)(ws + 45800000ull);
  u16*   W4H  = (u16*)(ws + 45950000ull); u16* W4L = (u16*)(ws + 46250000ull);
  u16*   W5H  = (u16*)(ws + 46550000ull); u16* W5L = (u16*)(ws + 47150000ull);
  u16*   W6H  = (u16*)(ws + 47750000ull); u16* W6L = (u16*)(ws + 48950000ull);
  u16*   WgfH = (u16*)(ws + 50150000ull); u16* WgfL = (u16*)(ws + 50450000ull);
  u16*   WgbH = (u16*)(ws + 50750000ull); u16* WgbL = (u16*)(ws + 51050000ull);
  float* b3   = ws + 51350000ull;
  float* b4   = ws + 51360000ull;
  float* b5   = ws + 51370000ull;
  float* b6   = ws + 51380000ull;
  float* bgf  = ws + 51390000ull;
  float* bgb  = ws + 51400000ull;
  float* weff = ws + 51420000ull;
  float* beff = ws + 51430000ull;
  u16*   rowsH = (u16*)d_out;                         // 9,994,240 u (in d_out)
  float* outF  = (float*)d_out;

  // ---- weight preparation ----
  k_fold<<<1, 256, 0, stream>>>(c1w, c1b, c2w, c2b, weff, beff);
  k_prepW<<<1152, 256, 0, stream>>>(c3w, c3b, bn1g,bn1b,bn1m,bn1v, 1, 256,128, W3H,W3L, b3);
  k_prepW<<<2304, 256, 0, stream>>>(c4w, c4b, nullptr,nullptr,nullptr,nullptr, 0, 256,256, W4H,W4L, b4);
  k_prepW<<<4608, 256, 0, stream>>>(c5w, c5b, bn2g,bn2b,bn2m,bn2v, 1, 512,256, W5H,W5L, b5);
  k_prepW<<<9216, 256, 0, stream>>>(c6w, c6b, bn3g,bn3b,bn3m,bn3v, 1, 512,512, W6H,W6L, b6);
  k_prepWg<<<2048, 256, 0, stream>>>(wihf, bihf, bhhf, WgfH, WgfL, bgf);
  k_prepWg<<<2048, 256, 0, stream>>>(wihb, bihb, bhhb, WgbH, WgbL, bgb);
  k_transU<<<2048, 256, 0, stream>>>(whhf, whhb, UT);

  // ---- conv chain, two batch-halves of 8 images ----
  for (int hb = 0; hb < 2; ++hb){
    int nB = hb*8;
    const float* xh = x + (size_t)nB*98304ull;
    k_conv2pool<<<dim3(8,16,128), 256, 0, stream>>>(xh, weff, beff, p1H, p1L);
    // conv3+bn1: p1(8,31,255,128) -> y3(8,29,253,256)
    k_igemm<<<dim3(2,29,16), 256, 0, stream>>>(p1H,p1L, W3H,W3L, b3,
        y3H,y3L, nullptr, 31,255,128,256,29,253, 9,0,4);
    // conv4: y3 -> y4(8,27,251,256)
    k_igemm<<<dim3(2,27,16), 256, 0, stream>>>(y3H,y3L, W4H,W4L, b4,
        y4H,y4L, nullptr, 29,253,256,256,27,251, 9,0,8);
    // maxpool 2x2/1: y4 -> p2(8,26,250,256)
    k_pool2<<<6500, 256, 0, stream>>>(y4H,y4L, p2H,p2L);
    // conv5+bn2+stride2: p2 -> p3(8,12,124,512)
    k_igemm<<<dim3(1,12,32), 256, 0, stream>>>(p2H,p2L, W5H,W5L, b5,
        p3H,p3L, nullptr, 26,250,256,512,12,124, 9,1,8);
    // conv6+bn3(+implicit transpose via NHWC): p3 -> rows(80 rows of 122x512)
    k_igemm<<<dim3(1,10,32), 256, 0, stream>>>(p3H,p3L, W6H,W6L, b6,
        rowsH + (size_t)nB*624640ull, rowsL + (size_t)nB*624640ull, nullptr,
        12,124,512,512,10,122, 9,0,16);
  }

  // ---- input projection GEMMs: rows(19520x512) @ W^T(512x1024) -> pre fp32 ----
  k_igemm<<<dim3(153,1,8), 256, 0, stream>>>(rowsH,rowsL, WgfH,WgfL, bgf,
      nullptr,nullptr, pre, 1,19520,512,1024,1,19520, 1,0,16);
  k_igemm<<<dim3(153,1,8), 256, 0, stream>>>(rowsH,rowsL, WgbH,WgbL, bgb,
      nullptr,nullptr, pre + 19988480ull, 1,19520,512,1024,1,19520, 1,0,16);

  // ---- recurrence ----
  k_lstm<<<160, 256, 0, stream>>>(pre, UT, outF);
}

// Round 4
// 2928.747 us; speedup vs baseline: 4.1655x; 1.1077x over previous
//
#include <hip/hip_runtime.h>
#include <cmath>

#define DEV __device__ __forceinline__

typedef __attribute__((ext_vector_type(8))) short  short8;
typedef __attribute__((ext_vector_type(8))) unsigned short ushort8;
typedef __attribute__((ext_vector_type(4))) float  f32x4;

DEV float sigm(float x){ return 1.0f/(1.0f + __expf(-x)); }
DEV float tanhx(float x){
  x = fminf(fmaxf(x, -15.0f), 15.0f);
  float e = __expf(2.0f*x);
  return (e - 1.0f)/(e + 1.0f);
}
DEV unsigned short f2bf(float f){
  unsigned u = __float_as_uint(f);
  return (unsigned short)((u + 0x7fffu + ((u>>16)&1u)) >> 16);
}
DEV float bf2f(unsigned short h){ return __uint_as_float(((unsigned)h)<<16); }
DEV void split2(float v, unsigned short& hi, unsigned short& lo){
  hi = f2bf(v); lo = f2bf(v - bf2f(hi));
}

#define GLDS(SRC, DST) __builtin_amdgcn_global_load_lds( \
  (const __attribute__((address_space(1))) unsigned int*)(SRC), \
  (__attribute__((address_space(3))) unsigned int*)(DST), 16, 0, 0)

// ---------------------------------------------------------------------------
// fold conv1 (1x1,3->64) into conv2 (3x3,64->128)
// ---------------------------------------------------------------------------
__global__ __launch_bounds__(256) void k_fold(const float* __restrict__ w1,
    const float* __restrict__ b1, const float* __restrict__ w2,
    const float* __restrict__ b2, float* __restrict__ weff, float* __restrict__ beff)
{
  int tid = threadIdx.x;
  for (int i = tid; i < 3456; i += 256){
    int oc = i / 27, rem = i % 27, c = rem / 9, k = rem % 9;
    float s = 0.f;
    for (int m = 0; m < 64; ++m)
      s += w2[(oc*64 + m)*9 + k] * w1[m*3 + c];
    weff[i] = s;
  }
  for (int i = tid; i < 128; i += 256){
    float s = b2[i];
    for (int m = 0; m < 64; ++m){
      float t = 0.f;
      for (int k = 0; k < 9; ++k) t += w2[(i*64 + m)*9 + k];
      s += t * b1[m];
    }
    beff[i] = s;
  }
}

// ---------------------------------------------------------------------------
// conv weight prep: W9T[k][oc][ic] = bf16split(w[oc][ic][k] * bnscale[oc]),
// bias_eff[oc] = cb*sc + shift.
// ---------------------------------------------------------------------------
__global__ __launch_bounds__(256) void k_prepW(const float* __restrict__ w,
    const float* __restrict__ cb, const float* __restrict__ bng,
    const float* __restrict__ bnb, const float* __restrict__ bnm,
    const float* __restrict__ bnv, int useBN, int OC, int IC,
    unsigned short* __restrict__ WH, unsigned short* __restrict__ WL,
    float* __restrict__ bout)
{
  int idx = blockIdx.x*256 + threadIdx.x;
  int tot = OC*IC*9;
  if (idx < tot){
    int k = idx % 9; int t2 = idx/9; int ic = t2 % IC; int oc = t2/IC;
    float sc = useBN ? bng[oc]*rsqrtf(bnv[oc]+1e-5f) : 1.0f;
    unsigned short h,l; split2(w[idx]*sc, h, l);
    size_t o = ((size_t)k*OC + oc)*IC + ic;
    WH[o]=h; WL[o]=l;
  }
  if (idx < OC){
    float sc = useBN ? bng[idx]*rsqrtf(bnv[idx]+1e-5f) : 1.0f;
    float sh = useBN ? (bnb[idx]-bnm[idx]*sc) : 0.f;
    bout[idx] = cb[idx]*sc + sh;
  }
}

// gemm weight prep: WH/WL[oc][ic] = split(w), b = bih+bhh
__global__ __launch_bounds__(256) void k_prepWg(const float* __restrict__ w,
    const float* __restrict__ b1, const float* __restrict__ b2,
    unsigned short* __restrict__ WH, unsigned short* __restrict__ WL,
    float* __restrict__ bout)
{
  int idx = blockIdx.x*256 + threadIdx.x;
  if (idx < 1024*512){
    unsigned short h,l; split2(w[idx], h, l);
    WH[idx]=h; WL[idx]=l;
  }
  if (idx < 1024) bout[idx] = b1[idx] + b2[idx];
}

// ---------------------------------------------------------------------------
// fused conv2' (3x3,IC=3,OC=128) + maxpool2x2/2 -> p1 NHWC bf16 hi/lo (per half)
// ---------------------------------------------------------------------------
__global__ __launch_bounds__(256) void k_conv2pool(const float* __restrict__ x,
    const float* __restrict__ weff, const float* __restrict__ beff,
    unsigned short* __restrict__ p1H, unsigned short* __restrict__ p1L)
{
  __shared__ float wl[8*27];
  __shared__ float sm[8][4][66];
  int tx = threadIdx.x & 63, ty = threadIdx.x >> 6;
  int ocb = blockIdx.z & 15, n = blockIdx.z >> 4;   // n local 0..7
  int oc0 = ocb*8;
  if (threadIdx.x < 216) wl[threadIdx.x] = weff[oc0*27 + threadIdx.x];
  __syncthreads();
  int ow = blockIdx.x*64 + tx;
  int oh = blockIdx.y*4 + ty;
  int owc = min(ow, 509), ohc = min(oh, 61);
  const float* xp = x + ((size_t)n*3*64 + ohc)*512 + owc;
  float iv[27];
  #pragma unroll
  for (int c = 0; c < 3; ++c)
    #pragma unroll
    for (int kh = 0; kh < 3; ++kh)
      #pragma unroll
      for (int kw = 0; kw < 3; ++kw)
        iv[c*9 + kh*3 + kw] = xp[((size_t)c*64 + kh)*512 + kw];
  #pragma unroll
  for (int j = 0; j < 8; ++j){
    float s = beff[oc0 + j];
    const float* wp = &wl[j*27];
    #pragma unroll
    for (int k = 0; k < 27; ++k) s += iv[k]*wp[k];
    sm[j][ty][tx] = s;
  }
  __syncthreads();
  int pr0 = blockIdx.y*2, pc0 = blockIdx.x*32;
  for (int i = threadIdx.x; i < 512; i += 256){
    int pc = i & 31, rem = i >> 5, q = rem & 1, j = rem >> 1;
    int prow = pr0 + q, pcol = pc0 + pc;
    if (prow < 31 && pcol < 255){
      float m0 = fmaxf(sm[j][2*q  ][2*pc], sm[j][2*q  ][2*pc+1]);
      float m1 = fmaxf(sm[j][2*q+1][2*pc], sm[j][2*q+1][2*pc+1]);
      unsigned short h,l; split2(fmaxf(m0,m1), h, l);
      size_t o = (((size_t)(n*31 + prow)*255 + pcol)<<7) + oc0 + j;
      p1H[o] = h; p1L[o] = l;
    }
  }
}

// ---------------------------------------------------------------------------
// split-bf16 implicit-GEMM conv / GEMM.  C[pix][oc] = sum_{k9,ic} A*W.
// BM=128 pix (1 oh row), BN=128 oc, BK=32. 256 thr / 4 waves, mfma 16x16x32.
// A = NHWC bf16 (hi,lo), W = [k][oc][ic] bf16 (hi,lo).  3 products/chunk.
// global_load_lds staging, linear LDS + inverse-swizzled source + swz read.
// ---------------------------------------------------------------------------
__global__ __launch_bounds__(256) void k_igemm(
    const unsigned short* __restrict__ inH, const unsigned short* __restrict__ inL,
    const unsigned short* __restrict__ wH,  const unsigned short* __restrict__ wL,
    const float* __restrict__ bias,
    unsigned short* __restrict__ outH, unsigned short* __restrict__ outL,
    float* __restrict__ outF,
    int IH, int IW, int IC, int OC, int OH, int OW,
    int K9, int sub, int nICc)
{
  __shared__ unsigned short lds[2][16384];  // [AH 4096][AL 4096][BH 4096][BL 4096]
  const int tid  = threadIdx.x;
  const int wv   = tid >> 6, lane = tid & 63;
  const int wr   = wv >> 1,  wc   = wv & 1;
  const int kg   = lane >> 4;
  const int ocTiles = OC >> 7;
  const int ow0 = blockIdx.x << 7;
  const int oh  = blockIdx.y;
  const int ocb = blockIdx.z % ocTiles;
  const int n   = blockIdx.z / ocTiles;
  const int oc0 = ocb << 7;

  // staging source bases (per-lane, inverse-swizzled slot)
  const int sp = tid >> 2, ss = tid & 3;
  size_t aBase[2], bBase[2];
  #pragma unroll
  for (int q = 0; q < 2; ++q){
    int p = q*64 + sp;
    int opix = min(ow0 + p, OW-1);
    int sw = ss ^ ((p>>1)&3);
    aBase[q] = ((size_t)(n*IH + (oh<<sub))*IW + ((size_t)opix<<sub))*IC + sw*8;
    int o = q*64 + sp;
    int swb = ss ^ ((o>>1)&3);
    bBase[q] = (size_t)(oc0 + o)*IC + swb*8;
  }
  // fragment read offsets (swizzled), ushort units
  int aoff[4], boff[4];
  #pragma unroll
  for (int mi = 0; mi < 4; ++mi){
    int pr = wr*64 + mi*16 + (lane&15);
    aoff[mi] = pr*32 + ((kg ^ ((pr>>1)&3))*8);
  }
  #pragma unroll
  for (int nj = 0; nj < 4; ++nj){
    int orow = wc*64 + nj*16 + (lane&15);
    boff[nj] = orow*32 + ((kg ^ ((orow>>1)&3))*8);
  }

  auto STAGE = [&](int buf, int kk, int ic0){
    size_t aOff = ((size_t)((kk/3)*IW + (kk%3)))*IC + ic0;
    size_t bOff = ((size_t)kk*OC)*IC + ic0;
    unsigned short* d0 = &lds[buf][wv*512];
    #pragma unroll
    for (int q = 0; q < 2; ++q){
      GLDS(inH + aBase[q] + aOff, d0 + q*2048);
      GLDS(inL + aBase[q] + aOff, d0 + 4096  + q*2048);
      GLDS(wH  + bBase[q] + bOff, d0 + 8192  + q*2048);
      GLDS(wL  + bBase[q] + bOff, d0 + 12288 + q*2048);
    }
  };

  f32x4 acc[4][4] = {};
  const int NT = K9 * nICc;
  STAGE(0, 0, 0);
  int cur = 0;
  for (int t = 0; t < NT; ++t){
    __syncthreads();
    short8 aH[4], aL[4], bH[4], bL[4];
    #pragma unroll
    for (int mi = 0; mi < 4; ++mi){
      aH[mi] = *(const short8*)&lds[cur][aoff[mi]];
      aL[mi] = *(const short8*)&lds[cur][4096 + aoff[mi]];
    }
    #pragma unroll
    for (int nj = 0; nj < 4; ++nj){
      bH[nj] = *(const short8*)&lds[cur][8192  + boff[nj]];
      bL[nj] = *(const short8*)&lds[cur][12288 + boff[nj]];
    }
    if (t+1 < NT){
      int tn = t+1, kk = tn / nICc, icc = tn - kk*nICc;
      STAGE(cur^1, kk, icc*32);
    }
    #pragma unroll
    for (int mi = 0; mi < 4; ++mi)
      #pragma unroll
      for (int nj = 0; nj < 4; ++nj){
        acc[mi][nj] = __builtin_amdgcn_mfma_f32_16x16x32_bf16(aH[mi], bH[nj], acc[mi][nj],0,0,0);
        acc[mi][nj] = __builtin_amdgcn_mfma_f32_16x16x32_bf16(aL[mi], bH[nj], acc[mi][nj],0,0,0);
        acc[mi][nj] = __builtin_amdgcn_mfma_f32_16x16x32_bf16(aH[mi], bL[nj], acc[mi][nj],0,0,0);
      }
    cur ^= 1;
  }

  // epilogue: C[m][oc] with row=(lane>>4)*4+j, col=lane&15 (m89-verified)
  const int ocL = oc0 + wc*64 + (lane&15);
  const int rb  = wr*64 + ((lane>>4)<<2);
  #pragma unroll
  for (int nj = 0; nj < 4; ++nj){
    int oc = ocL + nj*16;
    float bs = bias[oc];
    #pragma unroll
    for (int mi = 0; mi < 4; ++mi)
      #pragma unroll
      for (int j = 0; j < 4; ++j){
        int pix = ow0 + rb + mi*16 + j;
        if (pix < OW){
          size_t oi = ((size_t)(n*OH + oh)*OW + pix)*OC + oc;
          float v = acc[mi][nj][j] + bs;
          if (outF) outF[oi] = v;
          else { unsigned short h,l; split2(v,h,l); outH[oi]=h; outL[oi]=l; }
        }
      }
  }
}

// ---------------------------------------------------------------------------
// maxpool 2x2/1 on NHWC bf16 hi/lo, per half: (8,27,251,256)->(8,26,250,256)
// ---------------------------------------------------------------------------
__global__ __launch_bounds__(256) void k_pool2(const unsigned short* __restrict__ yH,
    const unsigned short* __restrict__ yL,
    unsigned short* __restrict__ pH, unsigned short* __restrict__ pL)
{
  int idx = blockIdx.x*256 + threadIdx.x;       // over 8*26*250*32
  if (idx >= 1664000) return;
  int g = idx & 31; int t2 = idx >> 5;
  int pw = t2 % 250; t2 /= 250; int ph = t2 % 26; int n = t2 / 26;
  size_t base = (((size_t)(n*27 + ph)*251 + pw)<<8) + g*8;
  float v[8];
  #pragma unroll
  for (int e = 0; e < 8; ++e) v[e] = -3.4e38f;
  #pragma unroll
  for (int r = 0; r < 2; ++r)
    #pragma unroll
    for (int c = 0; c < 2; ++c){
      size_t o = base + ((size_t)(r*251 + c)<<8);
      ushort8 hv = *(const ushort8*)&yH[o];
      ushort8 lv = *(const ushort8*)&yL[o];
      #pragma unroll
      for (int e = 0; e < 8; ++e)
        v[e] = fmaxf(v[e], bf2f(hv[e]) + bf2f(lv[e]));
    }
  ushort8 oh8, ol8;
  #pragma unroll
  for (int e = 0; e < 8; ++e){ unsigned short h,l; split2(v[e],h,l); oh8[e]=h; ol8[e]=l; }
  size_t ob = (((size_t)(n*26 + ph)*250 + pw)<<8) + g*8;
  *(ushort8*)&pH[ob] = oh8;
  *(ushort8*)&pL[ob] = ol8;
}

// ---------------------------------------------------------------------------
// transpose whh (1024x256) -> UT[dir](256x1024)
// ---------------------------------------------------------------------------
__global__ __launch_bounds__(256) void k_transU(const float* __restrict__ Uf,
    const float* __restrict__ Ub, float* __restrict__ UT)
{
  int idx = blockIdx.x*256 + threadIdx.x;
  int d = idx >> 18; int rem = idx & 262143;
  int k = rem >> 10, g = rem & 1023;
  const float* U = d ? Ub : Uf;
  UT[idx] = U[g*256 + k];
}

// ---------------------------------------------------------------------------
// bidirectional LSTM recurrence; pre layout [dir][m=r*122+t][1024] fp32.
// 160 blocks (80 row-pairs x 2 dirs) x 1024 threads (16 waves).
// Thread g owns gate-dim g (of 1024) for BOTH rows of its pair:
//   per k: 1 coalesced U load + 1 float4 LDS read (h of both rows, 2 k's)
//   + 4 FMA.  Gates go through an 8KB LDS roundtrip; c-state in registers
//   of threads < 512.  U (2MB both dirs) is L2-resident per XCD.
// ---------------------------------------------------------------------------
__global__ __launch_bounds__(1024) void k_lstm(const float* __restrict__ pre,
    const float* __restrict__ UT, float* __restrict__ out)
{
  int b = blockIdx.x;
  int dir = (b >= 80) ? 1 : 0;
  int r0 = (b - dir*80)*2;
  int g = threadIdx.x;                     // gate dim 0..1023
  const float* Ut   = UT  + (size_t)dir*262144;
  const float* preD = pre + (size_t)dir*19988480ull;
  __shared__ __align__(16) float2 hsh[256];   // h[k] for row0 (.x) / row1 (.y)
  __shared__ float gl[2][1024];
  if (g < 256) hsh[g] = make_float2(0.f, 0.f);
  __syncthreads();
  float c = 0.f;                           // c-state (threads < 512)
  const int row = g >> 8, j = g & 255;     // used when g < 512

  const float* p0 = preD + ((size_t)r0*122)*1024 + g;
  for (int s = 0; s < 122; ++s){
    int t = dir ? (121 - s) : s;
    float a0 = p0[(size_t)t*1024];
    float a1 = p0[(size_t)t*1024 + 124928];   // row r0+1 (= +122*1024)
    const float* up = Ut + g;
    #pragma unroll 4
    for (int k = 0; k < 256; k += 2){
      float4 hv = *(const float4*)&hsh[k];    // h0[k],h1[k],h0[k+1],h1[k+1]
      float u0 = up[0];
      float u1 = up[1024];
      a0 = fmaf(hv.x, u0, a0);
      a1 = fmaf(hv.y, u0, a1);
      a0 = fmaf(hv.z, u1, a0);
      a1 = fmaf(hv.w, u1, a1);
      up += 2048;
    }
    gl[0][g] = a0; gl[1][g] = a1;
    __syncthreads();
    if (g < 512){
      float i_ = sigm(gl[row][j]);
      float f_ = sigm(gl[row][256+j]);
      float g_ = tanhx(gl[row][512+j]);
      float o_ = sigm(gl[row][768+j]);
      c = f_*c + i_*g_;
      float nh = o_*tanhx(c);
      if (row == 0) hsh[j].x = nh; else hsh[j].y = nh;
      out[((size_t)(r0+row)*122 + t)*512 + dir*256 + j] = nh;
    }
    __syncthreads();
  }
}

// ---------------------------------------------------------------------------
// host.  ws layout (float units), peak ~51.44M floats = 206 MB (< proven 231MB):
//  pre @0 (39.98M) | conv arena (per batch-half, reused): y3@0, y4@15.1M,
//  p1@29.0M, p2@0, p3@15.1M | rowsLo @40.0M | weights/UT/biases @45.1M+
// ---------------------------------------------------------------------------
extern "C" void kernel_launch(void* const* d_in, const int* in_sizes, int n_in,
                              void* d_out, int out_size, void* d_ws, size_t ws_size,
                              hipStream_t stream)
{
  const float* x    = (const float*)d_in[0];
  const float* c1w  = (const float*)d_in[1];
  const float* c1b  = (const float*)d_in[2];
  const float* c2w  = (const float*)d_in[3];
  const float* c2b  = (const float*)d_in[4];
  const float* c3w  = (const float*)d_in[5];
  const float* c3b  = (const float*)d_in[6];
  const float* bn1g = (const float*)d_in[7];
  const float* bn1b = (const float*)d_in[8];
  const float* bn1m = (const float*)d_in[9];
  const float* bn1v = (const float*)d_in[10];
  const float* c4w  = (const float*)d_in[11];
  const float* c4b  = (const float*)d_in[12];
  const float* c5w  = (const float*)d_in[13];
  const float* c5b  = (const float*)d_in[14];
  const float* bn2g = (const float*)d_in[15];
  const float* bn2b = (const float*)d_in[16];
  const float* bn2m = (const float*)d_in[17];
  const float* bn2v = (const float*)d_in[18];
  const float* c6w  = (const float*)d_in[19];
  const float* c6b  = (const float*)d_in[20];
  const float* bn3g = (const float*)d_in[21];
  const float* bn3b = (const float*)d_in[22];
  const float* bn3m = (const float*)d_in[23];
  const float* bn3v = (const float*)d_in[24];
  const float* wihf = (const float*)d_in[25];
  const float* whhf = (const float*)d_in[26];
  const float* bihf = (const float*)d_in[27];
  const float* bhhf = (const float*)d_in[28];
  const float* wihb = (const float*)d_in[29];
  const float* whhb = (const float*)d_in[30];
  const float* bihb = (const float*)d_in[31];
  const float* bhhb = (const float*)d_in[32];

  float* ws = (float*)d_ws;
  typedef unsigned short u16;

  float* pre  = ws;                                   // 39,976,960 f
  u16*   y3H  = (u16*)(ws);            u16* y3L = y3H + 15026176ull;
  u16*   y4H  = (u16*)(ws + 15100000ull); u16* y4L = y4H + 13879296ull;
  u16*   p1H  = (u16*)(ws + 29000000ull); u16* p1L = p1H + 8094720ull;
  u16*   p2H  = (u16*)(ws);            u16* p2L = p2H + 13312000ull;
  u16*   p3H  = (u16*)(ws + 15100000ull); u16* p3L = p3H + 6094848ull;
  u16*   rowsL= (u16*)(ws + 40000000ull);             // 9,994,240 u
  float* UT   = ws + 45100000ull;
  u16*   W3H  = (u16*)(ws + 45650000ull); u16* W3L = (u16*)(ws + 45800000ull);
  u16*   W4H  = (u16*)(ws + 45950000ull); u16* W4L = (u16*)(ws + 46250000ull);
  u16*   W5H  = (u16*)(ws + 46550000ull); u16* W5L = (u16*)(ws + 47150000ull);
  u16*   W6H  = (u16*)(ws + 47750000ull); u16* W6L = (u16*)(ws + 48950000ull);
  u16*   WgfH = (u16*)(ws + 50150000ull); u16* WgfL = (u16*)(ws + 50450000ull);
  u16*   WgbH = (u16*)(ws + 50750000ull); u16* WgbL = (u16*)(ws + 51050000ull);
  float* b3   = ws + 51350000ull;
  float* b4   = ws + 51360000ull;
  float* b5   = ws + 51370000ull;
  float* b6   = ws + 51380000ull;
  float* bgf  = ws + 51390000ull;
  float* bgb  = ws + 51400000ull;
  float* weff = ws + 51420000ull;
  float* beff = ws + 51430000ull;
  u16*   rowsH = (u16*)d_out;                         // 9,994,240 u (in d_out)
  float* outF  = (float*)d_out;

  // ---- weight preparation ----
  k_fold<<<1, 256, 0, stream>>>(c1w, c1b, c2w, c2b, weff, beff);
  k_prepW<<<1152, 256, 0, stream>>>(c3w, c3b, bn1g,bn1b,bn1m,bn1v, 1, 256,128, W3H,W3L, b3);
  k_prepW<<<2304, 256, 0, stream>>>(c4w, c4b, nullptr,nullptr,nullptr,nullptr, 0, 256,256, W4H,W4L, b4);
  k_prepW<<<4608, 256, 0, stream>>>(c5w, c5b, bn2g,bn2b,bn2m,bn2v, 1, 512,256, W5H,W5L, b5);
  k_prepW<<<9216, 256, 0, stream>>>(c6w, c6b, bn3g,bn3b,bn3m,bn3v, 1, 512,512, W6H,W6L, b6);
  k_prepWg<<<2048, 256, 0, stream>>>(wihf, bihf, bhhf, WgfH, WgfL, bgf);
  k_prepWg<<<2048, 256, 0, stream>>>(wihb, bihb, bhhb, WgbH, WgbL, bgb);
  k_transU<<<2048, 256, 0, stream>>>(whhf, whhb, UT);

  // ---- conv chain, two batch-halves of 8 images ----
  for (int hb = 0; hb < 2; ++hb){
    int nB = hb*8;
    const float* xh = x + (size_t)nB*98304ull;
    k_conv2pool<<<dim3(8,16,128), 256, 0, stream>>>(xh, weff, beff, p1H, p1L);
    // conv3+bn1: p1(8,31,255,128) -> y3(8,29,253,256)
    k_igemm<<<dim3(2,29,16), 256, 0, stream>>>(p1H,p1L, W3H,W3L, b3,
        y3H,y3L, nullptr, 31,255,128,256,29,253, 9,0,4);
    // conv4: y3 -> y4(8,27,251,256)
    k_igemm<<<dim3(2,27,16), 256, 0, stream>>>(y3H,y3L, W4H,W4L, b4,
        y4H,y4L, nullptr, 29,253,256,256,27,251, 9,0,8);
    // maxpool 2x2/1: y4 -> p2(8,26,250,256)
    k_pool2<<<6500, 256, 0, stream>>>(y4H,y4L, p2H,p2L);
    // conv5+bn2+stride2: p2 -> p3(8,12,124,512)
    k_igemm<<<dim3(1,12,32), 256, 0, stream>>>(p2H,p2L, W5H,W5L, b5,
        p3H,p3L, nullptr, 26,250,256,512,12,124, 9,1,8);
    // conv6+bn3(+implicit transpose via NHWC): p3 -> rows(80 rows of 122x512)
    k_igemm<<<dim3(1,10,32), 256, 0, stream>>>(p3H,p3L, W6H,W6L, b6,
        rowsH + (size_t)nB*624640ull, rowsL + (size_t)nB*624640ull, nullptr,
        12,124,512,512,10,122, 9,0,16);
  }

  // ---- input projection GEMMs: rows(19520x512) @ W^T(512x1024) -> pre fp32 ----
  k_igemm<<<dim3(153,1,8), 256, 0, stream>>>(rowsH,rowsL, WgfH,WgfL, bgf,
      nullptr,nullptr, pre, 1,19520,512,1024,1,19520, 1,0,16);
  k_igemm<<<dim3(153,1,8), 256, 0, stream>>>(rowsH,rowsL, WgbH,WgbL, bgb,
      nullptr,nullptr, pre + 19988480ull, 1,19520,512,1024,1,19520, 1,0,16);

  // ---- recurrence ----
  k_lstm<<<160, 1024, 0, stream>>>(pre, UT, outF);
}